// Round 9
// baseline (358.721 us; speedup 1.0000x reference)
//
#include <hip/hip_runtime.h>

#define HIDDEN 128
#define NEG_SLOPE 0.2f
#define P_SORT 256          // blocks for phase-1 bucket sort
#define LCOL_CAP 512        // per-block edge-coeff LDS cache (16 nodes, deg~16 -> ~256)

typedef unsigned short ushort_t;
typedef __attribute__((ext_vector_type(8))) short short8;
typedef __attribute__((ext_vector_type(4))) float floatx4;

static inline size_t align_up(size_t x, size_t a){ return (x + a - 1) & ~(a - 1); }

__device__ __forceinline__ ushort_t f2b(float f){
  unsigned u = __float_as_uint(f);
  unsigned r = (u + 0x7FFFu + ((u >> 16) & 1u)) >> 16;
  return (ushort_t)r;
}

__device__ __forceinline__ float b2f(ushort_t u){
  return __uint_as_float(((unsigned)u) << 16);
}

// int8 row-quantized feature FMA: 8 sbytes in two uints, coeff a includes row scale
__device__ __forceinline__ void fma8q(float* acc, unsigned ux, unsigned uy, float a){
  int x = (int)ux, y = (int)uy;
  acc[0] += a * (float)((x << 24) >> 24);
  acc[1] += a * (float)((x << 16) >> 24);
  acc[2] += a * (float)((x <<  8) >> 24);
  acc[3] += a * (float)( x        >> 24);
  acc[4] += a * (float)((y << 24) >> 24);
  acc[5] += a * (float)((y << 16) >> 24);
  acc[6] += a * (float)((y <<  8) >> 24);
  acc[7] += a * (float)( y        >> 24);
}

// 16 sbytes (uint4 = 64B half-row slice per lane) -> 16 accum floats
__device__ __forceinline__ void fma16q(float* acc, uint4 v, float a){
  fma8q(acc,     v.x, v.y, a);
  fma8q(acc + 8, v.z, v.w, a);
}

__device__ __forceinline__ unsigned packq4(const float* f, float qi){
  unsigned a = 0; int q;
  q = (int)rintf(f[0]*qi); a |= ((unsigned)q & 255u);
  q = (int)rintf(f[1]*qi); a |= ((unsigned)q & 255u) << 8;
  q = (int)rintf(f[2]*qi); a |= ((unsigned)q & 255u) << 16;
  q = (int)rintf(f[3]*qi); a |= ((unsigned)q & 255u) << 24;
  return a;
}

__device__ __forceinline__ uint4 packq16(const float* f, float qi){
  uint4 r;
  r.x = packq4(f,      qi);
  r.y = packq4(f + 4,  qi);
  r.z = packq4(f + 8,  qi);
  r.w = packq4(f + 12, qi);
  return r;
}

__device__ __forceinline__ uint4 pack8(const float* f){
  uint4 u;
  u.x = (unsigned)f2b(f[0]) | ((unsigned)f2b(f[1]) << 16);
  u.y = (unsigned)f2b(f[2]) | ((unsigned)f2b(f[3]) << 16);
  u.z = (unsigned)f2b(f[4]) | ((unsigned)f2b(f[5]) << 16);
  u.w = (unsigned)f2b(f[6]) | ((unsigned)f2b(f[7]) << 16);
  return u;
}

// ============ CSR build: two-pass bucketed counting sort ============
// merged: blocks [0, P_SORT) do the bucket count; blocks [P_SORT, P_SORT+256)
// do the independent weight cast (4 mats fp32 -> transposed bf16).

__global__ __launch_bounds__(256) void k_b1cnt_cast(const int* __restrict__ dst,
                                                    int* __restrict__ bcnt,
                                                    const float* __restrict__ Wg,
                                                    const float* __restrict__ Wc,
                                                    ushort_t* __restrict__ Wt,
                                                    int E, int epb, int nbkt){
  int t = threadIdx.x;
  if (blockIdx.x >= P_SORT){
    int i = (blockIdx.x - P_SORT)*256 + t;     // 4*16384 elements
    int mat = i >> 14, idx = i & 16383;
    int k = idx >> 7, n = idx & 127;
    float v = (mat == 0) ? Wg[idx] : Wc[(mat-1)*16384 + idx];
    Wt[mat*16384 + n*128 + k] = f2b(v);
    return;
  }
  __shared__ unsigned c[256];
  c[t] = 0;
  __syncthreads();
  int e0 = blockIdx.x * epb;
  int e1 = min(E, e0 + epb);
  for (int e = e0 + t; e < e1; e += 256) atomicAdd(&c[dst[e] >> 8], 1u);
  __syncthreads();
  if (t < nbkt) bcnt[t * P_SORT + blockIdx.x] = (int)c[t];
}

__global__ void k_scan1(const int* __restrict__ in, int* __restrict__ incl,
                        int* __restrict__ blockSums, int M){
  __shared__ int sd[256];
  int t = threadIdx.x;
  int i = blockIdx.x*256 + t;
  int v = (i < M) ? in[i] : 0;
  sd[t] = v; __syncthreads();
  for (int off = 1; off < 256; off <<= 1){
    int add = (t >= off) ? sd[t-off] : 0;
    __syncthreads();
    sd[t] += add;
    __syncthreads();
  }
  if (i < M) incl[i] = sd[t];
  if (t == 255) blockSums[blockIdx.x] = sd[255];
}

// phase-1 scatter; bucket offsets (exclusive scan of blockSums) inline in LDS.
__global__ __launch_bounds__(256) void k_b1place(const int* __restrict__ src,
                                                 const int* __restrict__ dst,
                                                 const float* __restrict__ w,
                                                 const int* __restrict__ incl,
                                                 const int* __restrict__ bcnt,
                                                 const int* __restrict__ blockSums,
                                                 int2* __restrict__ tpw,
                                                 int E, int epb, int nbkt){
  __shared__ int base_[256];
  __shared__ unsigned c[256];
  __shared__ int sOf[256];
  int t = threadIdx.x;
  c[t] = 0;
  int bs = (t < nbkt) ? blockSums[t] : 0;
  sOf[t] = bs;
  __syncthreads();
  for (int off = 1; off < 256; off <<= 1){
    int add = (t >= off) ? sOf[t-off] : 0;
    __syncthreads();
    sOf[t] += add;
    __syncthreads();
  }
  if (t < nbkt){
    int idx = t * P_SORT + blockIdx.x;
    base_[t] = incl[idx] - bcnt[idx] + (sOf[t] - bs);   // + exclusive bucket offset
  }
  __syncthreads();
  int e0 = blockIdx.x * epb;
  int e1 = min(E, e0 + epb);
  for (int e = e0 + t; e < e1; e += 256){
    int d = dst[e];
    int b = d >> 8;
    unsigned r = atomicAdd(&c[b], 1u);
    int pos = base_[b] + (int)r;
    tpw[pos] = make_int2((int)((unsigned)src[e] | ((unsigned)(d & 255) << 16)),
                         __float_as_int(w[e]));
  }
}

// phase-2 fine sort: counting sort on key (row, src>>12); bucket range from
// inline scan of blockSums.
__global__ __launch_bounds__(256) void k_b2(const int2* __restrict__ tpw,
                                            const int* __restrict__ blockSums,
                                            int2* __restrict__ col_sw,
                                            int* __restrict__ rowp,
                                            float* __restrict__ dinv,
                                            int N, int E, int nbkt){
  __shared__ int cnt[4096];      // 256 rows x 16 src-slices
  __shared__ int tsum[256];
  __shared__ float wsum[256];
  __shared__ int sOf[256];
  int b = blockIdx.x, t = threadIdx.x;
  #pragma unroll
  for (int i = 0; i < 16; i++) cnt[t*16 + i] = 0;
  wsum[t] = 0.f;
  sOf[t] = (t < nbkt) ? blockSums[t] : 0;
  __syncthreads();
  for (int off = 1; off < 256; off <<= 1){
    int add = (t >= off) ? sOf[t-off] : 0;
    __syncthreads();
    sOf[t] += add;
    __syncthreads();
  }
  int e1 = sOf[b];
  int e0 = (b > 0) ? sOf[b-1] : 0;
  for (int e = e0 + t; e < e1; e += 256){
    int2 pw = tpw[e];
    unsigned dl = ((unsigned)pw.x >> 16) & 255u;
    unsigned s  = ((unsigned)pw.x & 0xFFFFu) >> 12;     // src slice 0..15
    atomicAdd(&cnt[(dl << 4) | s], 1);
  }
  __syncthreads();
  int loc[16]; int run = 0;
  #pragma unroll
  for (int i = 0; i < 16; i++){ loc[i] = run; run += cnt[t*16 + i]; }
  tsum[t] = run;
  __syncthreads();
  for (int off = 1; off < 256; off <<= 1){
    int add = (t >= off) ? tsum[t-off] : 0;
    __syncthreads();
    tsum[t] += add;
    __syncthreads();
  }
  int base = tsum[t] - run;                              // exclusive over rows
  #pragma unroll
  for (int i = 0; i < 16; i++) cnt[t*16 + i] = base + loc[i];
  int node = b*256 + t;
  if (node < N) rowp[node] = e0 + base;
  if (b == 0 && t == 0) rowp[N] = E;
  __syncthreads();
  for (int e = e0 + t; e < e1; e += 256){
    int2 pw = tpw[e];
    unsigned dl = ((unsigned)pw.x >> 16) & 255u;
    unsigned srcv = (unsigned)pw.x & 0xFFFFu;
    unsigned s = srcv >> 12;
    int pos = e0 + atomicAdd(&cnt[(dl << 4) | s], 1);    // old value == slot
    col_sw[pos] = make_int2((int)srcv, pw.y);
    atomicAdd(&wsum[dl], __int_as_float(pw.y));
  }
  __syncthreads();
  if (node < N) dinv[node] = rsqrtf(wsum[t] + 1.0f);     // +1 = self-loop weight
}

// ------- MFMA GEMM (GAT layer): xp = x @ W_gat; outputs int8 xp rows split as
// compact lo/hi 64B arrays, attr4 = {a_src dot, dinv, int8 scale, 0}, and sdst. -------
__global__ __launch_bounds__(128) void k_gemm1(const float* __restrict__ Ain,
                                               const ushort_t* __restrict__ Wt,
                                               uint4* __restrict__ zlo,
                                               uint4* __restrict__ zhi,
                                               const float* __restrict__ a_src,
                                               const float* __restrict__ a_dst,
                                               const float* __restrict__ dinv,
                                               float4* __restrict__ attr4,
                                               float* __restrict__ sdst, int M){
  __shared__ uint4 zq8v[64][8];                 // 64 rows x 128B int8 staging
  char (*zq8)[128] = (char(*)[128])zq8v;
  int wave = threadIdx.x >> 6, l = threadIdx.x & 63;
  int q = l >> 4, lm = l & 15;
  int rowBase = blockIdx.x*64 + wave*32;
  floatx4 acc[2][8];
  #pragma unroll
  for (int mt = 0; mt < 2; mt++)
    #pragma unroll
    for (int nt = 0; nt < 8; nt++) acc[mt][nt] = (floatx4){0.f,0.f,0.f,0.f};

  #pragma unroll
  for (int kc = 0; kc < 4; kc++){
    int k0 = kc*32 + q*8;
    short8 a[2];
    #pragma unroll
    for (int mt = 0; mt < 2; mt++){
      long r = rowBase + mt*16 + lm;
      if (r < M){
        const float* ap = Ain + r*128 + k0;
        float4 u = *(const float4*)ap;
        float4 v = *(const float4*)(ap + 4);
        short8 tv;
        tv[0]=(short)f2b(u.x); tv[1]=(short)f2b(u.y); tv[2]=(short)f2b(u.z); tv[3]=(short)f2b(u.w);
        tv[4]=(short)f2b(v.x); tv[5]=(short)f2b(v.y); tv[6]=(short)f2b(v.z); tv[7]=(short)f2b(v.w);
        a[mt] = tv;
      } else a[mt] = (short8){0,0,0,0,0,0,0,0};
    }
    #pragma unroll
    for (int nt = 0; nt < 8; nt++){
      short8 b = *(const short8*)(Wt + (nt*16 + lm)*128 + k0);
      acc[0][nt] = __builtin_amdgcn_mfma_f32_16x16x32_bf16(a[0], b, acc[0][nt], 0, 0, 0);
      acc[1][nt] = __builtin_amdgcn_mfma_f32_16x16x32_bf16(a[1], b, acc[1][nt], 0, 0, 0);
    }
  }
  // ---- int8 row quantization (C layout: row = rowBase+mt*16+q*4+r, col = nt*16+lm) ----
  float rms[2][4];
  #pragma unroll
  for (int mt = 0; mt < 2; mt++){
    #pragma unroll
    for (int r = 0; r < 4; r++){
      float rm = 0.f;
      #pragma unroll
      for (int nt = 0; nt < 8; nt++) rm = fmaxf(rm, fabsf(acc[mt][nt][r]));
      #pragma unroll
      for (int off = 1; off <= 8; off <<= 1) rm = fmaxf(rm, __shfl_xor(rm, off, 64));
      float qi = (rm > 0.f) ? 127.f/rm : 0.f;
      int lrow = wave*32 + mt*16 + q*4 + r;
      #pragma unroll
      for (int nt = 0; nt < 8; nt++)
        zq8[lrow][nt*16 + lm] = (char)(int)rintf(acc[mt][nt][r]*qi);
      rms[mt][r] = rm * (1.f/127.f);
    }
  }
  // ---- fused attention row dots ----
  float as8[8], ad8[8];
  #pragma unroll
  for (int nt = 0; nt < 8; nt++){ as8[nt] = a_src[nt*16 + lm]; ad8[nt] = a_dst[nt*16 + lm]; }
  #pragma unroll
  for (int mt = 0; mt < 2; mt++){
    #pragma unroll
    for (int r = 0; r < 4; r++){
      float ps = 0.f, pd = 0.f;
      #pragma unroll
      for (int nt = 0; nt < 8; nt++){
        ps += acc[mt][nt][r] * as8[nt];
        pd += acc[mt][nt][r] * ad8[nt];
      }
      #pragma unroll
      for (int off = 1; off <= 8; off <<= 1){
        ps += __shfl_xor(ps, off, 64);
        pd += __shfl_xor(pd, off, 64);
      }
      long row = rowBase + mt*16 + q*4 + r;
      if (lm == 0 && row < M){
        attr4[row] = make_float4(ps, dinv[row], rms[mt][r], 0.f);
        sdst[row] = pd;
      }
    }
  }
  __syncthreads();
  // ---- coalesced dump of int8 rows into lo/hi compact arrays ----
  {
    int t = threadIdx.x;
    int lrow = t >> 1, half = t & 1;
    long row = (long)blockIdx.x*64 + lrow;
    if (row < M){
      uint4* dq = (half == 0) ? (zlo + row*4) : (zhi + row*4);
      #pragma unroll
      for (int k = 0; k < 4; k++) dq[k] = zq8v[lrow][half*4 + k];
    }
  }
}

// ======= GAT aggregation: 2 nodes/wave, 8 slots x 4 lanes x 16B (r1 shape) =======
// Sequential lo/hi half-passes over compact 64B half-row arrays; softmax denom
// accumulated in the lo pass; exp recomputed in the hi pass (cheap, L2-hot attr).
__global__ __launch_bounds__(256) void k_agg0(const uint4* __restrict__ zlo,
                                              const uint4* __restrict__ zhi,
                                              const int* __restrict__ rowp,
                                              const int2* __restrict__ col_sw,
                                              const float4* __restrict__ attr4,
                                              const float* __restrict__ sdst_,
                                              const float* __restrict__ bias,
                                              ushort_t* __restrict__ out,
                                              uint4* __restrict__ glo,
                                              uint4* __restrict__ ghi,
                                              float* __restrict__ scd0, int N){
  int wave = threadIdx.x >> 6, l = threadIdx.x & 63;
  int h = l >> 5, s = (l >> 2) & 7, q2 = l & 3;
  int n = blockIdx.x*8 + wave*2 + h;
  bool valid = (n < N);
  int rs = 0, re = 0;
  float4 an = make_float4(0.f,0.f,0.f,0.f);
  float sdd = 0.f, pself = 0.f;
  if (valid){
    rs = rowp[n]; re = rowp[n+1];
    an = attr4[n]; sdd = sdst_[n];
    float es = an.x + sdd;
    es = (es >= 0.f) ? es : NEG_SLOPE*es;
    pself = __expf(es);
  }
  int last = (re > rs) ? re - 1 : 0;
  float acc_lo[16], acc_hi[16];
  #pragma unroll
  for (int k = 0; k < 16; k++){ acc_lo[k] = 0.f; acc_hi[k] = 0.f; }
  float ps = 0.f;
  // ---- lo half-pass (also accumulates softmax denom) ----
  for (int base = rs; base < re; base += 24){
    int2 p[3]; float4 at[3]; uint4 v[3];
    #pragma unroll
    for (int j = 0; j < 3; j++){
      int e = base + s + 8*j;
      p[j] = col_sw[min(e, last)];
    }
    #pragma unroll
    for (int j = 0; j < 3; j++) at[j] = attr4[p[j].x];
    #pragma unroll
    for (int j = 0; j < 3; j++) v[j] = zlo[(size_t)p[j].x*4 + q2];
    #pragma unroll
    for (int j = 0; j < 3; j++){
      int e = base + s + 8*j;
      float ee = at[j].x + sdd;
      ee = (ee >= 0.f) ? ee : NEG_SLOPE*ee;
      float pe = (e < re) ? __expf(ee) : 0.f;
      ps += pe;
      fma16q(acc_lo, v[j], pe * at[j].z);
    }
  }
  // ---- hi half-pass (exp recomputed; col/attr are L2 hits) ----
  for (int base = rs; base < re; base += 24){
    int2 p[3]; float4 at[3]; uint4 v[3];
    #pragma unroll
    for (int j = 0; j < 3; j++){
      int e = base + s + 8*j;
      p[j] = col_sw[min(e, last)];
    }
    #pragma unroll
    for (int j = 0; j < 3; j++) at[j] = attr4[p[j].x];
    #pragma unroll
    for (int j = 0; j < 3; j++) v[j] = zhi[(size_t)p[j].x*4 + q2];
    #pragma unroll
    for (int j = 0; j < 3; j++){
      int e = base + s + 8*j;
      float ee = at[j].x + sdd;
      ee = (ee >= 0.f) ? ee : NEG_SLOPE*ee;
      float pe = (e < re) ? __expf(ee) : 0.f;
      fma16q(acc_hi, v[j], pe * at[j].z);
    }
  }
  // reduce over 8 slots (xor bits 2,3,4 stay within the 32-lane half)
  ps += __shfl_xor(ps, 4, 64);
  ps += __shfl_xor(ps, 8, 64);
  ps += __shfl_xor(ps, 16, 64);
  #pragma unroll
  for (int k = 0; k < 16; k++){
    acc_lo[k] += __shfl_xor(acc_lo[k], 4, 64);
    acc_lo[k] += __shfl_xor(acc_lo[k], 8, 64);
    acc_lo[k] += __shfl_xor(acc_lo[k], 16, 64);
    acc_hi[k] += __shfl_xor(acc_hi[k], 4, 64);
    acc_hi[k] += __shfl_xor(acc_hi[k], 8, 64);
    acc_hi[k] += __shfl_xor(acc_hi[k], 16, 64);
  }
  if (s == 0 && valid){
    float inv = 1.f / (ps + pself);
    #pragma unroll
    for (int k = 0; k < 16; k++){ acc_lo[k] *= inv; acc_hi[k] *= inv; }
    float cs = pself * inv * an.z;
    fma16q(acc_lo, zlo[(size_t)n*4 + q2], cs);
    fma16q(acc_hi, zhi[(size_t)n*4 + q2], cs);
    const float4* bl = (const float4*)(bias + q2*16);
    const float4* bh = (const float4*)(bias + 64 + q2*16);
    #pragma unroll
    for (int g = 0; g < 4; g++){
      float4 b0 = bl[g], b1 = bh[g];
      acc_lo[g*4+0]+=b0.x; acc_lo[g*4+1]+=b0.y; acc_lo[g*4+2]+=b0.z; acc_lo[g*4+3]+=b0.w;
      acc_hi[g*4+0]+=b1.x; acc_hi[g*4+1]+=b1.y; acc_hi[g*4+2]+=b1.z; acc_hi[g*4+3]+=b1.w;
    }
    // bf16 h0 (for JK)
    ((uint4*)out)[(size_t)n*16 + q2*2]         = pack8(acc_lo);
    ((uint4*)out)[(size_t)n*16 + q2*2 + 1]     = pack8(acc_lo + 8);
    ((uint4*)out)[(size_t)n*16 + 8 + q2*2]     = pack8(acc_hi);
    ((uint4*)out)[(size_t)n*16 + 8 + q2*2 + 1] = pack8(acc_hi + 8);
    // int8 row quantization (row max over 128 dims: local then across 4 q2 lanes)
    float rm = 0.f;
    #pragma unroll
    for (int k = 0; k < 16; k++) rm = fmaxf(rm, fmaxf(fabsf(acc_lo[k]), fabsf(acc_hi[k])));
    rm = fmaxf(rm, __shfl_xor(rm, 1, 64));
    rm = fmaxf(rm, __shfl_xor(rm, 2, 64));
    float qi = (rm > 0.f) ? 127.f/rm : 0.f;
    glo[(size_t)n*4 + q2] = packq16(acc_lo, qi);
    ghi[(size_t)n*4 + q2] = packq16(acc_hi, qi);
    if (q2 == 0) scd0[n] = rm * (1.f/127.f) * an.y;     // sc0 * dinv[n]
  }
}

// ======= fused GCN layer, int8 lo/hi gather (r1 shape): h' = relu((A h) W + b) =======
// Block pre-pass caches edge coeffs {src, w*scd_prev[src]} in LDS. Phase 1:
// per wave 2 rounds x 2 nodes, each node = sequential lo/hi half-passes
// (4 lanes x 16B per edge, 8 slots). Phase 2: inline MFMA x W.
// MODE 1: write bf16 h' + int8 g'_lo/hi + scd'. MODE 2: last layer + JK max.
template<int MODE>
__global__ __launch_bounds__(256) void k_fagg(const uint4* __restrict__ glo,
                                              const uint4* __restrict__ ghi,
                                              const float* __restrict__ scd_prev,
                                              const int* __restrict__ rowp,
                                              const int2* __restrict__ col_sw,
                                              const float* __restrict__ dinv,
                                              const ushort_t* __restrict__ Wl,
                                              const float* __restrict__ bias,
                                              ushort_t* __restrict__ out,
                                              uint4* __restrict__ golo,
                                              uint4* __restrict__ gohi,
                                              float* __restrict__ scd_out,
                                              const ushort_t* __restrict__ j0,
                                              const ushort_t* __restrict__ j1,
                                              const ushort_t* __restrict__ j2,
                                              float* __restrict__ yout, int N){
  __shared__ ushort_t At[16][136];             // +8 pad: break LDS bank aliasing
  __shared__ uint4 q8v[16][8];                 // int8 output staging (16 x 128B)
  __shared__ unsigned rmaxs[16];
  __shared__ int2 lcol[LCOL_CAP];              // block-local edge coeff cache
  char (*q8s)[128] = (char(*)[128])q8v;
  int wave = threadIdx.x >> 6, l = threadIdx.x & 63;
  int h = l >> 5, s = (l >> 2) & 7, q2 = l & 3;
  int sub = l >> 4, q = l & 15;                // phase-2 decomposition
  int tile = blockIdx.x * 16;

  // ---- block pre-pass: edge coeffs into LDS (edge-parallel, scd gather L2-hot) ----
  int E0 = rowp[tile];
  int E1 = rowp[min(tile + 16, N)];
  int ecnt = E1 - E0;
  bool fast = (ecnt <= LCOL_CAP);
  if (fast){
    for (int i = threadIdx.x; i < ecnt; i += 256){
      int2 sw = col_sw[E0 + i];
      lcol[i] = make_int2(sw.x, __float_as_int(__int_as_float(sw.y) * scd_prev[sw.x]));
    }
  }
  if (threadIdx.x < 16) rmaxs[threadIdx.x] = 0u;
  __syncthreads();

  // ---- phase 1: 2 rounds x 2 nodes/wave; lo then hi half-pass per node ----
  #pragma unroll
  for (int rnd = 0; rnd < 2; rnd++){
    int row = wave*4 + rnd*2 + h;
    int n = tile + row;
    int rs = 0, re = 0; float dn = 0.f, sprev = 0.f;
    if (n < N){ rs = rowp[n]; re = rowp[n+1]; dn = dinv[n]; sprev = scd_prev[n]; }
    int last = (re > rs) ? re - 1 : 0;
    float acc_lo[16], acc_hi[16];
    #pragma unroll
    for (int k = 0; k < 16; k++){ acc_lo[k] = 0.f; acc_hi[k] = 0.f; }
    if (fast){
      for (int base = rs; base < re; base += 24){
        int2 p[3]; uint4 v[3];
        #pragma unroll
        for (int j = 0; j < 3; j++){
          int e = base + s + 8*j;
          p[j] = lcol[min(e, last) - E0];
        }
        #pragma unroll
        for (int j = 0; j < 3; j++) v[j] = glo[(size_t)p[j].x*4 + q2];
        #pragma unroll
        for (int j = 0; j < 3; j++){
          int e = base + s + 8*j;
          fma16q(acc_lo, v[j], (e < re) ? __int_as_float(p[j].y) : 0.f);
        }
      }
      for (int base = rs; base < re; base += 24){
        int2 p[3]; uint4 v[3];
        #pragma unroll
        for (int j = 0; j < 3; j++){
          int e = base + s + 8*j;
          p[j] = lcol[min(e, last) - E0];
        }
        #pragma unroll
        for (int j = 0; j < 3; j++) v[j] = ghi[(size_t)p[j].x*4 + q2];
        #pragma unroll
        for (int j = 0; j < 3; j++){
          int e = base + s + 8*j;
          fma16q(acc_hi, v[j], (e < re) ? __int_as_float(p[j].y) : 0.f);
        }
      }
    } else {
      // freak-degree fallback: inline coeff from col_sw + scd_prev
      for (int base = rs; base < re; base += 24){
        int2 p[3]; uint4 v[3];
        #pragma unroll
        for (int j = 0; j < 3; j++){
          int e = base + s + 8*j;
          int2 sw = col_sw[min(e, last)];
          p[j] = make_int2(sw.x, __float_as_int(__int_as_float(sw.y) * scd_prev[sw.x]));
        }
        #pragma unroll
        for (int j = 0; j < 3; j++) v[j] = glo[(size_t)p[j].x*4 + q2];
        #pragma unroll
        for (int j = 0; j < 3; j++){
          int e = base + s + 8*j;
          fma16q(acc_lo, v[j], (e < re) ? __int_as_float(p[j].y) : 0.f);
        }
      }
      for (int base = rs; base < re; base += 24){
        int2 p[3]; uint4 v[3];
        #pragma unroll
        for (int j = 0; j < 3; j++){
          int e = base + s + 8*j;
          int2 sw = col_sw[min(e, last)];
          p[j] = make_int2(sw.x, __float_as_int(__int_as_float(sw.y) * scd_prev[sw.x]));
        }
        #pragma unroll
        for (int j = 0; j < 3; j++) v[j] = ghi[(size_t)p[j].x*4 + q2];
        #pragma unroll
        for (int j = 0; j < 3; j++){
          int e = base + s + 8*j;
          fma16q(acc_hi, v[j], (e < re) ? __int_as_float(p[j].y) : 0.f);
        }
      }
    }
    #pragma unroll
    for (int k = 0; k < 16; k++){
      acc_lo[k] += __shfl_xor(acc_lo[k], 4, 64);
      acc_lo[k] += __shfl_xor(acc_lo[k], 8, 64);
      acc_lo[k] += __shfl_xor(acc_lo[k], 16, 64);
      acc_hi[k] += __shfl_xor(acc_hi[k], 4, 64);
      acc_hi[k] += __shfl_xor(acc_hi[k], 8, 64);
      acc_hi[k] += __shfl_xor(acc_hi[k], 16, 64);
    }
    if (s == 0){
      if (n < N){
        fma16q(acc_lo, glo[(size_t)n*4 + q2], sprev);   // self-loop term
        fma16q(acc_hi, ghi[(size_t)n*4 + q2], sprev);
      }
      #pragma unroll
      for (int k = 0; k < 16; k++){ acc_lo[k] *= dn; acc_hi[k] *= dn; }
      *(uint4*)&At[row][q2*16]      = pack8(acc_lo);    // zeros for n >= N
      *(uint4*)&At[row][q2*16 + 8]  = pack8(acc_lo + 8);
      *(uint4*)&At[row][64 + q2*16]     = pack8(acc_hi);
      *(uint4*)&At[row][64 + q2*16 + 8] = pack8(acc_hi + 8);
    }
  }
  __syncthreads();

  // ---- phase 2: [16x128] @ [128x128] ; wave covers 32 output cols ----
  floatx4 co[2];
  co[0] = (floatx4){0.f,0.f,0.f,0.f};
  co[1] = (floatx4){0.f,0.f,0.f,0.f};
  #pragma unroll
  for (int kc = 0; kc < 4; kc++){
    int k0 = kc*32 + sub*8;
    short8 a = *(const short8*)&At[q][k0];
    #pragma unroll
    for (int ntl = 0; ntl < 2; ntl++){
      int nt = wave*2 + ntl;
      short8 b = *(const short8*)(Wl + (size_t)(nt*16 + q)*128 + k0);
      co[ntl] = __builtin_amdgcn_mfma_f32_16x16x32_bf16(a, b, co[ntl], 0, 0, 0);
    }
  }
  // C layout: col = lane&15 (=q), row = sub*4 + r
  float vv[4][2];
  #pragma unroll
  for (int r = 0; r < 4; r++){
    int row = sub*4 + r;
    int node = tile + row;
    float lmax = 0.f;
    #pragma unroll
    for (int ntl = 0; ntl < 2; ntl++){
      int colg = wave*32 + ntl*16 + q;
      float v = co[ntl][r] + bias[colg];
      v = fmaxf(v, 0.f);                       // all GCN layers ReLU'd
      vv[r][ntl] = v;
      lmax = fmaxf(lmax, v);
      if (node < N){
        size_t idx = (size_t)node*128 + colg;
        if (MODE == 1){
          out[idx] = f2b(v);                   // bf16 h' for JK
        } else {
          float m = fmaxf(fmaxf(b2f(j0[idx]), b2f(j1[idx])),
                          fmaxf(b2f(j2[idx]), v));
          yout[idx] = m;
        }
      }
    }
    if (MODE == 1) atomicMax(&rmaxs[row], __float_as_uint(lmax));  // v>=0: bits ordered
  }
  if (MODE == 1){
    __syncthreads();
    #pragma unroll
    for (int r = 0; r < 4; r++){
      int row = sub*4 + r;
      float rm = __uint_as_float(rmaxs[row]);
      float qi = (rm > 0.f) ? 127.f/rm : 0.f;
      #pragma unroll
      for (int ntl = 0; ntl < 2; ntl++){
        int colg = wave*32 + ntl*16 + q;
        q8s[row][colg] = (char)(int)rintf(vv[r][ntl]*qi);
      }
    }
    if (threadIdx.x < 16){
      int node = tile + threadIdx.x;
      if (node < N){
        float rm = __uint_as_float(rmaxs[threadIdx.x]);
        scd_out[node] = rm * (1.f/127.f) * dinv[node];
      }
    }
    __syncthreads();
    if (threadIdx.x < 128){
      int row = threadIdx.x >> 3, c = threadIdx.x & 7;
      int node = tile + row;
      if (node < N){
        if (c < 4) golo[(size_t)node*4 + c]       = q8v[row][c];
        else       gohi[(size_t)node*4 + (c - 4)] = q8v[row][c];
      }
    }
  }
}

extern "C" void kernel_launch(void* const* d_in, const int* in_sizes, int n_in,
                              void* d_out, int out_size, void* d_ws, size_t ws_size,
                              hipStream_t stream){
  const float* x      = (const float*)d_in[0];
  const int*   eidx   = (const int*)d_in[1];
  const float* emask  = (const float*)d_in[2];
  const float* W_gat  = (const float*)d_in[3];
  const float* a_src  = (const float*)d_in[4];
  const float* a_dst  = (const float*)d_in[5];
  const float* b_gat  = (const float*)d_in[6];
  const float* W_gcn  = (const float*)d_in[7];
  const float* b_gcn  = (const float*)d_in[8];
  int N = in_sizes[0] / HIDDEN;
  int E = in_sizes[1] / 2;
  const int* src = eidx;
  const int* dst = eidx + E;

  char* p = (char*)d_ws;
  auto carve = [&](size_t bytes)->char*{ char* q = p; p += align_up(bytes, 512); return q; };
  ushort_t* h0   = (ushort_t*)carve((size_t)N*HIDDEN*2);
  ushort_t* h1   = (ushort_t*)carve((size_t)N*HIDDEN*2);
  ushort_t* h2   = (ushort_t*)carve((size_t)N*HIDDEN*2);
  ushort_t* Wt   = (ushort_t*)carve((size_t)4*HIDDEN*HIDDEN*2);
  uint4* z_lo    = (uint4*)carve((size_t)N*64);   // int8 half-row arrays (64B/node)
  uint4* z_hi    = (uint4*)carve((size_t)N*64);
  uint4* g0_lo   = (uint4*)carve((size_t)N*64);
  uint4* g0_hi   = (uint4*)carve((size_t)N*64);
  uint4* g1_lo   = (uint4*)carve((size_t)N*64);
  uint4* g1_hi   = (uint4*)carve((size_t)N*64);
  uint4* g2_lo   = (uint4*)carve((size_t)N*64);
  uint4* g2_hi   = (uint4*)carve((size_t)N*64);
  float* scd0    = (float*)carve((size_t)N*4);
  float* scd1    = (float*)carve((size_t)N*4);
  float* scd2    = (float*)carve((size_t)N*4);
  float4* attr4  = (float4*)carve((size_t)N*16);
  float* sdst    = (float*)carve((size_t)N*4);
  float* dinv    = (float*)carve((size_t)N*4);
  int*   rowp    = (int*)  carve((size_t)(N+1)*4);
  int2*  col_sw  = (int2*) carve((size_t)E*8);
  int2*  tpw     = (int2*) carve((size_t)E*8);
  int nbkt = (N + 255) >> 8;                       // 196
  int M    = nbkt * P_SORT;                        // 50176
  int*   bcnt  = (int*)carve((size_t)M*4);
  int*   incl  = (int*)carve((size_t)M*4);
  int nbs = (M + 255) / 256;                       // == nbkt
  int*   blockSums = (int*)carve((size_t)nbs*4);
  (void)ws_size; (void)n_in; (void)out_size;

  int epb = (E + P_SORT - 1) / P_SORT;
  int gb  = (N + 63) / 64;
  int nwb = (N + 7) / 8;
  int nfb = (N + 15) / 16;

  // CSR build (atomic-free, full-chip); cast rides along in extra blocks
  k_b1cnt_cast<<<P_SORT + 256, 256, 0, stream>>>(dst, bcnt, W_gat, W_gcn, Wt, E, epb, nbkt);
  k_scan1  <<<nbs, 256, 0, stream>>>(bcnt, incl, blockSums, M);
  k_b1place<<<P_SORT, 256, 0, stream>>>(src, dst, emask, incl, bcnt, blockSums,
                                        tpw, E, epb, nbkt);
  k_b2     <<<nbkt, 256, 0, stream>>>(tpw, blockSums, col_sw, rowp, dinv, N, E, nbkt);

  // xp = x @ W_gat -> int8 lo/hi half-rows + attr4 {src-dot, dinv, scale} + sdst
  k_gemm1<<<gb, 128, 0, stream>>>(x, Wt, z_lo, z_hi, a_src, a_dst, dinv, attr4, sdst, N);

  // GAT aggregation (r1-shaped lo/hi sweeps), produces h0 bf16 + g0 int8 + scd0
  k_agg0<<<nwb, 256, 0, stream>>>(z_lo, z_hi, rowp, col_sw, attr4, sdst,
                                  b_gat, h0, g0_lo, g0_hi, scd0, N);

  // fused GCN layers: h' = relu((A h) W + b); edge coeffs cached per-block in LDS
  k_fagg<1><<<nfb, 256, 0, stream>>>(g0_lo, g0_hi, scd0, rowp, col_sw, dinv,
                                     Wt + (size_t)1*16384, b_gcn + 0,
                                     h1, g1_lo, g1_hi, scd1,
                                     nullptr, nullptr, nullptr, nullptr, N);
  k_fagg<1><<<nfb, 256, 0, stream>>>(g1_lo, g1_hi, scd1, rowp, col_sw, dinv,
                                     Wt + (size_t)2*16384, b_gcn + 128,
                                     h2, g2_lo, g2_hi, scd2,
                                     nullptr, nullptr, nullptr, nullptr, N);
  // last layer + fused JK max over {h0, h1, h2, h3} -> fp32 d_out
  k_fagg<2><<<nfb, 256, 0, stream>>>(g2_lo, g2_hi, scd2, rowp, col_sw, dinv,
                                     Wt + (size_t)3*16384, b_gcn + 256,
                                     nullptr, nullptr, nullptr, nullptr,
                                     h0, h1, h2, (float*)d_out, N);
}

// Round 10
// 315.537 us; speedup vs baseline: 1.1369x; 1.1369x over previous
//
#include <hip/hip_runtime.h>

#define HIDDEN 128
#define NEG_SLOPE 0.2f
#define P_SORT 256          // blocks for phase-1 bucket sort
#define LCOL_CAP 512        // per-block edge-coeff LDS cache (16 nodes, deg~16 -> ~256)

typedef unsigned short ushort_t;
typedef __attribute__((ext_vector_type(8))) short short8;
typedef __attribute__((ext_vector_type(4))) float floatx4;

static inline size_t align_up(size_t x, size_t a){ return (x + a - 1) & ~(a - 1); }

__device__ __forceinline__ ushort_t f2b(float f){
  unsigned u = __float_as_uint(f);
  unsigned r = (u + 0x7FFFu + ((u >> 16) & 1u)) >> 16;
  return (ushort_t)r;
}

__device__ __forceinline__ float b2f(ushort_t u){
  return __uint_as_float(((unsigned)u) << 16);
}

// int8 row-quantized feature FMA: 8 sbytes in a uint2, coeff a already includes row scale
__device__ __forceinline__ void fma8q(float* acc, uint2 v, float a){
  int x = (int)v.x, y = (int)v.y;
  acc[0] += a * (float)((x << 24) >> 24);
  acc[1] += a * (float)((x << 16) >> 24);
  acc[2] += a * (float)((x <<  8) >> 24);
  acc[3] += a * (float)( x        >> 24);
  acc[4] += a * (float)((y << 24) >> 24);
  acc[5] += a * (float)((y << 16) >> 24);
  acc[6] += a * (float)((y <<  8) >> 24);
  acc[7] += a * (float)( y        >> 24);
}

__device__ __forceinline__ uint2 packq8(const float* f, float qi){
  unsigned a = 0, b = 0;
  int q;
  q = (int)rintf(f[0]*qi); a |= ((unsigned)q & 255u);
  q = (int)rintf(f[1]*qi); a |= ((unsigned)q & 255u) << 8;
  q = (int)rintf(f[2]*qi); a |= ((unsigned)q & 255u) << 16;
  q = (int)rintf(f[3]*qi); a |= ((unsigned)q & 255u) << 24;
  q = (int)rintf(f[4]*qi); b |= ((unsigned)q & 255u);
  q = (int)rintf(f[5]*qi); b |= ((unsigned)q & 255u) << 8;
  q = (int)rintf(f[6]*qi); b |= ((unsigned)q & 255u) << 16;
  q = (int)rintf(f[7]*qi); b |= ((unsigned)q & 255u) << 24;
  uint2 r; r.x = a; r.y = b; return r;
}

__device__ __forceinline__ uint4 pack8(const float* f){
  uint4 u;
  u.x = (unsigned)f2b(f[0]) | ((unsigned)f2b(f[1]) << 16);
  u.y = (unsigned)f2b(f[2]) | ((unsigned)f2b(f[3]) << 16);
  u.z = (unsigned)f2b(f[4]) | ((unsigned)f2b(f[5]) << 16);
  u.w = (unsigned)f2b(f[6]) | ((unsigned)f2b(f[7]) << 16);
  return u;
}

// ============ CSR build: two-pass bucketed counting sort ============
// merged: blocks [0, P_SORT) do the bucket count; blocks [P_SORT, P_SORT+256)
// do the independent weight cast (4 mats fp32 -> transposed bf16).

__global__ __launch_bounds__(256) void k_b1cnt_cast(const int* __restrict__ dst,
                                                    int* __restrict__ bcnt,
                                                    const float* __restrict__ Wg,
                                                    const float* __restrict__ Wc,
                                                    ushort_t* __restrict__ Wt,
                                                    int E, int epb, int nbkt){
  int t = threadIdx.x;
  if (blockIdx.x >= P_SORT){
    int i = (blockIdx.x - P_SORT)*256 + t;     // 4*16384 elements
    int mat = i >> 14, idx = i & 16383;
    int k = idx >> 7, n = idx & 127;
    float v = (mat == 0) ? Wg[idx] : Wc[(mat-1)*16384 + idx];
    Wt[mat*16384 + n*128 + k] = f2b(v);
    return;
  }
  __shared__ unsigned c[256];
  c[t] = 0;
  __syncthreads();
  int e0 = blockIdx.x * epb;
  int e1 = min(E, e0 + epb);
  for (int e = e0 + t; e < e1; e += 256) atomicAdd(&c[dst[e] >> 8], 1u);
  __syncthreads();
  if (t < nbkt) bcnt[t * P_SORT + blockIdx.x] = (int)c[t];
}

__global__ void k_scan1(const int* __restrict__ in, int* __restrict__ incl,
                        int* __restrict__ blockSums, int M){
  __shared__ int sd[256];
  int t = threadIdx.x;
  int i = blockIdx.x*256 + t;
  int v = (i < M) ? in[i] : 0;
  sd[t] = v; __syncthreads();
  for (int off = 1; off < 256; off <<= 1){
    int add = (t >= off) ? sd[t-off] : 0;
    __syncthreads();
    sd[t] += add;
    __syncthreads();
  }
  if (i < M) incl[i] = sd[t];
  if (t == 255) blockSums[blockIdx.x] = sd[255];
}

// phase-1 scatter; bucket offsets (exclusive scan of blockSums, nbkt<=256 elems)
// recomputed inline in LDS (replaces the old k_scan2 kernel).
__global__ __launch_bounds__(256) void k_b1place(const int* __restrict__ src,
                                                 const int* __restrict__ dst,
                                                 const float* __restrict__ w,
                                                 const int* __restrict__ incl,
                                                 const int* __restrict__ bcnt,
                                                 const int* __restrict__ blockSums,
                                                 int2* __restrict__ tpw,
                                                 int E, int epb, int nbkt){
  __shared__ int base_[256];
  __shared__ unsigned c[256];
  __shared__ int sOf[256];
  int t = threadIdx.x;
  c[t] = 0;
  int bs = (t < nbkt) ? blockSums[t] : 0;
  sOf[t] = bs;
  __syncthreads();
  for (int off = 1; off < 256; off <<= 1){
    int add = (t >= off) ? sOf[t-off] : 0;
    __syncthreads();
    sOf[t] += add;
    __syncthreads();
  }
  if (t < nbkt){
    int idx = t * P_SORT + blockIdx.x;
    base_[t] = incl[idx] - bcnt[idx] + (sOf[t] - bs);   // + exclusive bucket offset
  }
  __syncthreads();
  int e0 = blockIdx.x * epb;
  int e1 = min(E, e0 + epb);
  for (int e = e0 + t; e < e1; e += 256){
    int d = dst[e];
    int b = d >> 8;
    unsigned r = atomicAdd(&c[b], 1u);
    int pos = base_[b] + (int)r;
    tpw[pos] = make_int2((int)((unsigned)src[e] | ((unsigned)(d & 255) << 16)),
                         __float_as_int(w[e]));
  }
}

// phase-2 fine sort: counting sort on key (row, src>>12); bucket range from
// inline scan of blockSums (e0 = sOf[b-1], e1 = sOf[b]).
__global__ __launch_bounds__(256) void k_b2(const int2* __restrict__ tpw,
                                            const int* __restrict__ blockSums,
                                            int2* __restrict__ col_sw,
                                            int* __restrict__ rowp,
                                            float* __restrict__ dinv,
                                            int N, int E, int nbkt){
  __shared__ int cnt[4096];      // 256 rows x 16 src-slices
  __shared__ int tsum[256];
  __shared__ float wsum[256];
  __shared__ int sOf[256];
  int b = blockIdx.x, t = threadIdx.x;
  #pragma unroll
  for (int i = 0; i < 16; i++) cnt[t*16 + i] = 0;
  wsum[t] = 0.f;
  sOf[t] = (t < nbkt) ? blockSums[t] : 0;
  __syncthreads();
  for (int off = 1; off < 256; off <<= 1){
    int add = (t >= off) ? sOf[t-off] : 0;
    __syncthreads();
    sOf[t] += add;
    __syncthreads();
  }
  int e1 = sOf[b];
  int e0 = (b > 0) ? sOf[b-1] : 0;
  for (int e = e0 + t; e < e1; e += 256){
    int2 pw = tpw[e];
    unsigned dl = ((unsigned)pw.x >> 16) & 255u;
    unsigned s  = ((unsigned)pw.x & 0xFFFFu) >> 12;     // src slice 0..15
    atomicAdd(&cnt[(dl << 4) | s], 1);
  }
  __syncthreads();
  int loc[16]; int run = 0;
  #pragma unroll
  for (int i = 0; i < 16; i++){ loc[i] = run; run += cnt[t*16 + i]; }
  tsum[t] = run;
  __syncthreads();
  for (int off = 1; off < 256; off <<= 1){
    int add = (t >= off) ? tsum[t-off] : 0;
    __syncthreads();
    tsum[t] += add;
    __syncthreads();
  }
  int base = tsum[t] - run;                              // exclusive over rows
  #pragma unroll
  for (int i = 0; i < 16; i++) cnt[t*16 + i] = base + loc[i];
  int node = b*256 + t;
  if (node < N) rowp[node] = e0 + base;
  if (b == 0 && t == 0) rowp[N] = E;
  __syncthreads();
  for (int e = e0 + t; e < e1; e += 256){
    int2 pw = tpw[e];
    unsigned dl = ((unsigned)pw.x >> 16) & 255u;
    unsigned srcv = (unsigned)pw.x & 0xFFFFu;
    unsigned s = srcv >> 12;
    int pos = e0 + atomicAdd(&cnt[(dl << 4) | s], 1);    // old value == slot
    col_sw[pos] = make_int2((int)srcv, pw.y);
    atomicAdd(&wsum[dl], __int_as_float(pw.y));
  }
  __syncthreads();
  if (node < N) dinv[node] = rsqrtf(wsum[t] + 1.0f);     // +1 = self-loop weight
}

// ------- MFMA GEMM (GAT layer): xp = x @ W_gat; outputs int8-quantized xp rows
// (zq), packed per-row table attr4 = {a_src dot, dinv, int8 scale, 0}, and sdst. -------
__global__ __launch_bounds__(128) void k_gemm1(const float* __restrict__ Ain,
                                               const ushort_t* __restrict__ Wt,
                                               unsigned* __restrict__ zq,   // N*32B (uint)
                                               const float* __restrict__ a_src,
                                               const float* __restrict__ a_dst,
                                               const float* __restrict__ dinv,
                                               float4* __restrict__ attr4,
                                               float* __restrict__ sdst, int M){
  __shared__ uint4 zq8v[64][8];                 // 64 rows x 128B int8 staging
  char (*zq8)[128] = (char(*)[128])zq8v;
  int wave = threadIdx.x >> 6, l = threadIdx.x & 63;
  int q = l >> 4, lm = l & 15;
  int rowBase = blockIdx.x*64 + wave*32;
  floatx4 acc[2][8];
  #pragma unroll
  for (int mt = 0; mt < 2; mt++)
    #pragma unroll
    for (int nt = 0; nt < 8; nt++) acc[mt][nt] = (floatx4){0.f,0.f,0.f,0.f};

  #pragma unroll
  for (int kc = 0; kc < 4; kc++){
    int k0 = kc*32 + q*8;
    short8 a[2];
    #pragma unroll
    for (int mt = 0; mt < 2; mt++){
      long r = rowBase + mt*16 + lm;
      if (r < M){
        const float* ap = Ain + r*128 + k0;
        float4 u = *(const float4*)ap;
        float4 v = *(const float4*)(ap + 4);
        short8 tv;
        tv[0]=(short)f2b(u.x); tv[1]=(short)f2b(u.y); tv[2]=(short)f2b(u.z); tv[3]=(short)f2b(u.w);
        tv[4]=(short)f2b(v.x); tv[5]=(short)f2b(v.y); tv[6]=(short)f2b(v.z); tv[7]=(short)f2b(v.w);
        a[mt] = tv;
      } else a[mt] = (short8){0,0,0,0,0,0,0,0};
    }
    #pragma unroll
    for (int nt = 0; nt < 8; nt++){
      short8 b = *(const short8*)(Wt + (nt*16 + lm)*128 + k0);
      acc[0][nt] = __builtin_amdgcn_mfma_f32_16x16x32_bf16(a[0], b, acc[0][nt], 0, 0, 0);
      acc[1][nt] = __builtin_amdgcn_mfma_f32_16x16x32_bf16(a[1], b, acc[1][nt], 0, 0, 0);
    }
  }
  // ---- int8 row quantization (C layout: row = rowBase+mt*16+q*4+r, col = nt*16+lm) ----
  float rms[2][4];
  #pragma unroll
  for (int mt = 0; mt < 2; mt++){
    #pragma unroll
    for (int r = 0; r < 4; r++){
      float rm = 0.f;
      #pragma unroll
      for (int nt = 0; nt < 8; nt++) rm = fmaxf(rm, fabsf(acc[mt][nt][r]));
      #pragma unroll
      for (int off = 1; off <= 8; off <<= 1) rm = fmaxf(rm, __shfl_xor(rm, off, 64));
      float qi = (rm > 0.f) ? 127.f/rm : 0.f;
      int lrow = wave*32 + mt*16 + q*4 + r;
      #pragma unroll
      for (int nt = 0; nt < 8; nt++)
        zq8[lrow][nt*16 + lm] = (char)(int)rintf(acc[mt][nt][r]*qi);
      rms[mt][r] = rm * (1.f/127.f);
    }
  }
  // ---- fused attention row dots ----
  float as8[8], ad8[8];
  #pragma unroll
  for (int nt = 0; nt < 8; nt++){ as8[nt] = a_src[nt*16 + lm]; ad8[nt] = a_dst[nt*16 + lm]; }
  #pragma unroll
  for (int mt = 0; mt < 2; mt++){
    #pragma unroll
    for (int r = 0; r < 4; r++){
      float ps = 0.f, pd = 0.f;
      #pragma unroll
      for (int nt = 0; nt < 8; nt++){
        ps += acc[mt][nt][r] * as8[nt];
        pd += acc[mt][nt][r] * ad8[nt];
      }
      #pragma unroll
      for (int off = 1; off <= 8; off <<= 1){
        ps += __shfl_xor(ps, off, 64);
        pd += __shfl_xor(pd, off, 64);
      }
      long row = rowBase + mt*16 + q*4 + r;
      if (lm == 0 && row < M){
        attr4[row] = make_float4(ps, dinv[row], rms[mt][r], 0.f);
        sdst[row] = pd;
      }
    }
  }
  __syncthreads();
  // ---- coalesced dump of int8 rows ----
  {
    int t = threadIdx.x;
    int lrow = t >> 1, half = t & 1;
    long row = (long)blockIdx.x*64 + lrow;
    if (row < M){
      uint4* dq = (uint4*)zq + row*8 + half*4;
      #pragma unroll
      for (int k = 0; k < 4; k++) dq[k] = zq8v[lrow][half*4 + k];
    }
  }
}

// ======= GAT aggregation, single fused sweep: wave per node, 16 lanes/edge =======
// Per edge slot: col -> {attr4 broadcast (L2), int8 feature (HBM)} in parallel.
__global__ __launch_bounds__(256) void k_agg0(const unsigned* __restrict__ zq,
                                              const int* __restrict__ rowp,
                                              const int2* __restrict__ col_sw,
                                              const float4* __restrict__ attr4,
                                              const float* __restrict__ sdst_,
                                              const float* __restrict__ bias,
                                              ushort_t* __restrict__ out,
                                              unsigned* __restrict__ g0,
                                              float* __restrict__ scd0, int N){
  int n = blockIdx.x*4 + (threadIdx.x >> 6);
  if (n >= N) return;
  int l = threadIdx.x & 63;
  int sub = l >> 4, q = l & 15;
  int rs = rowp[n], re = rowp[n+1];
  float4 an = attr4[n];
  float sdd = sdst_[n];
  float es = an.x + sdd;
  es = (es >= 0.f) ? es : NEG_SLOPE*es;
  float pself = __expf(es);

  const uint2* f8 = (const uint2*)zq;
  float acc[8] = {0.f,0.f,0.f,0.f,0.f,0.f,0.f,0.f};
  float ps = 0.f;
  int last = (re > rs) ? re - 1 : 0;
  for (int base = rs; base < re; base += 24){
    int2 p[6];
    #pragma unroll
    for (int j = 0; j < 6; j++){
      int e = base + sub + 4*j;
      p[j] = col_sw[min(e, last)];
    }
    float4 at[6];
    #pragma unroll
    for (int j = 0; j < 6; j++) at[j] = attr4[p[j].x];   // 16-lane broadcast, L2
    uint2 v[6];
    #pragma unroll
    for (int j = 0; j < 6; j++) v[j] = f8[(size_t)p[j].x*16 + q];
    #pragma unroll
    for (int j = 0; j < 6; j++){
      int e = base + sub + 4*j;
      float ee = at[j].x + sdd;
      ee = (ee >= 0.f) ? ee : NEG_SLOPE*ee;
      float pe = (e < re) ? __expf(ee) : 0.f;
      ps += pe;
      fma8q(acc, v[j], pe * at[j].z);
    }
  }
  // softmax denom: each slot's 16 lanes hold identical slot-sum; combine 4 slots
  ps += __shfl_xor(ps, 16, 64);
  ps += __shfl_xor(ps, 32, 64);
  float inv = 1.f / (ps + pself);
  #pragma unroll
  for (int j = 0; j < 8; j++){
    acc[j] += __shfl_xor(acc[j], 16, 64);
    acc[j] += __shfl_xor(acc[j], 32, 64);
  }
  if (sub == 0){
    #pragma unroll
    for (int j = 0; j < 8; j++) acc[j] *= inv;
    fma8q(acc, f8[(size_t)n*16 + q], pself * inv * an.z);
    float4 b0 = ((const float4*)bias)[q*2];
    float4 b1 = ((const float4*)bias)[q*2 + 1];
    acc[0]+=b0.x; acc[1]+=b0.y; acc[2]+=b0.z; acc[3]+=b0.w;
    acc[4]+=b1.x; acc[5]+=b1.y; acc[6]+=b1.z; acc[7]+=b1.w;
    ((uint4*)out)[(size_t)n*16 + q] = pack8(acc);        // bf16 h0 for JK
    float rm = 0.f;
    #pragma unroll
    for (int j = 0; j < 8; j++) rm = fmaxf(rm, fabsf(acc[j]));
    #pragma unroll
    for (int off = 1; off <= 8; off <<= 1) rm = fmaxf(rm, __shfl_xor(rm, off, 64));
    float qi = (rm > 0.f) ? 127.f/rm : 0.f;
    ((uint2*)g0)[(size_t)n*16 + q] = packq8(acc, qi);
    if (l == 0) scd0[n] = rm * (1.f/127.f) * an.y;       // sc0 * dinv[n]
  }
}

// ======= fused GCN layer, int8 gather: h' = relu((A h) W + b) =======
// Block pre-pass caches this block's edge coeffs {src, w*scd_prev[src]} in LDS
// (edge-parallel scd gather; replaces the separate k_ecoef kernel + col_eq
// round-trip). Phase 1 = round-6 proven loop. Phase 2 = inline MFMA x W.
// MODE 1: write bf16 h' + int8 g' + scd'. MODE 2: last layer + JK max -> fp32 out.
template<int MODE>
__global__ __launch_bounds__(256) void k_fagg(const unsigned* __restrict__ gin,
                                              const float* __restrict__ scd_prev,
                                              const int* __restrict__ rowp,
                                              const int2* __restrict__ col_sw,
                                              const float* __restrict__ dinv,
                                              const ushort_t* __restrict__ Wl,
                                              const float* __restrict__ bias,
                                              ushort_t* __restrict__ out,
                                              unsigned* __restrict__ gout,
                                              float* __restrict__ scd_out,
                                              const ushort_t* __restrict__ j0,
                                              const ushort_t* __restrict__ j1,
                                              const ushort_t* __restrict__ j2,
                                              float* __restrict__ yout, int N){
  __shared__ ushort_t At[16][136];             // +8 pad: break LDS bank aliasing
  __shared__ uint4 q8v[16][8];                 // int8 output staging (16 x 128B)
  __shared__ unsigned rmaxs[16];
  __shared__ int2 lcol[LCOL_CAP];              // block-local edge coeff cache
  char (*q8s)[128] = (char(*)[128])q8v;
  int wave = threadIdx.x >> 6, l = threadIdx.x & 63;
  int sub = l >> 4, q = l & 15;
  const uint2* f8 = (const uint2*)gin;
  int tile = blockIdx.x * 16;

  // ---- block pre-pass: edge coeffs into LDS (edge-parallel, scd gather L2-hot) ----
  int E0 = rowp[tile];
  int E1 = rowp[min(tile + 16, N)];
  int ecnt = E1 - E0;
  bool fast = (ecnt <= LCOL_CAP);
  if (fast){
    for (int i = threadIdx.x; i < ecnt; i += 256){
      int2 sw = col_sw[E0 + i];
      lcol[i] = make_int2(sw.x, __float_as_int(__int_as_float(sw.y) * scd_prev[sw.x]));
    }
  }
  if (threadIdx.x < 16) rmaxs[threadIdx.x] = 0u;
  __syncthreads();

  // ---- phase 1: aggregate 4 nodes per wave (round-6 proven loop) ----
  for (int i = 0; i < 4; i++){
    int row = wave*4 + i;
    int n = tile + row;
    int rs = 0, re = 0; float dn = 0.f, sprev = 0.f;
    if (n < N){ rs = rowp[n]; re = rowp[n+1]; dn = dinv[n]; sprev = scd_prev[n]; }
    int last = (re > rs) ? re - 1 : 0;
    float acc[8] = {0.f,0.f,0.f,0.f,0.f,0.f,0.f,0.f};
    if (fast){
      for (int base = rs; base < re; base += 24){
        int2 p[6];
        #pragma unroll
        for (int j = 0; j < 6; j++){
          int e = base + sub + 4*j;
          p[j] = lcol[min(e, last) - E0];
        }
        uint2 v[6];
        #pragma unroll
        for (int j = 0; j < 6; j++) v[j] = f8[(size_t)p[j].x*16 + q];
        #pragma unroll
        for (int j = 0; j < 6; j++){
          int e = base + sub + 4*j;
          fma8q(acc, v[j], (e < re) ? __int_as_float(p[j].y) : 0.f);
        }
      }
    } else {
      // freak-degree fallback (block has > LCOL_CAP edges): inline coeff
      for (int base = rs; base < re; base += 24){
        int2 p[6];
        #pragma unroll
        for (int j = 0; j < 6; j++){
          int e = base + sub + 4*j;
          int2 sw = col_sw[min(e, last)];
          p[j] = make_int2(sw.x, __float_as_int(__int_as_float(sw.y) * scd_prev[sw.x]));
        }
        uint2 v[6];
        #pragma unroll
        for (int j = 0; j < 6; j++) v[j] = f8[(size_t)p[j].x*16 + q];
        #pragma unroll
        for (int j = 0; j < 6; j++){
          int e = base + sub + 4*j;
          fma8q(acc, v[j], (e < re) ? __int_as_float(p[j].y) : 0.f);
        }
      }
    }
    #pragma unroll
    for (int j = 0; j < 8; j++){
      acc[j] += __shfl_xor(acc[j], 16, 64);
      acc[j] += __shfl_xor(acc[j], 32, 64);
    }
    if (sub == 0){
      if (n < N) fma8q(acc, f8[(size_t)n*16 + q], sprev);   // self-loop term
      #pragma unroll
      for (int j = 0; j < 8; j++) acc[j] *= dn;             // hoisted dinv[n]
      *(uint4*)&At[row][q*8] = pack8(acc);                  // zeros for n >= N
    }
  }
  __syncthreads();

  // ---- phase 2: [16x128] @ [128x128] ; wave covers 32 output cols ----
  floatx4 co[2];
  co[0] = (floatx4){0.f,0.f,0.f,0.f};
  co[1] = (floatx4){0.f,0.f,0.f,0.f};
  #pragma unroll
  for (int kc = 0; kc < 4; kc++){
    int k0 = kc*32 + sub*8;
    short8 a = *(const short8*)&At[q][k0];
    #pragma unroll
    for (int ntl = 0; ntl < 2; ntl++){
      int nt = wave*2 + ntl;
      short8 b = *(const short8*)(Wl + (size_t)(nt*16 + q)*128 + k0);
      co[ntl] = __builtin_amdgcn_mfma_f32_16x16x32_bf16(a, b, co[ntl], 0, 0, 0);
    }
  }
  // C layout: col = lane&15 (=q), row = sub*4 + r
  float vv[4][2];
  #pragma unroll
  for (int r = 0; r < 4; r++){
    int row = sub*4 + r;
    int node = tile + row;
    float lmax = 0.f;
    #pragma unroll
    for (int ntl = 0; ntl < 2; ntl++){
      int colg = wave*32 + ntl*16 + q;
      float v = co[ntl][r] + bias[colg];
      v = fmaxf(v, 0.f);                       // all GCN layers ReLU'd
      vv[r][ntl] = v;
      lmax = fmaxf(lmax, v);
      if (node < N){
        size_t idx = (size_t)node*128 + colg;
        if (MODE == 1){
          out[idx] = f2b(v);                   // bf16 h' for JK
        } else {
          float m = fmaxf(fmaxf(b2f(j0[idx]), b2f(j1[idx])),
                          fmaxf(b2f(j2[idx]), v));
          yout[idx] = m;
        }
      }
    }
    if (MODE == 1) atomicMax(&rmaxs[row], __float_as_uint(lmax));  // v>=0: bits ordered
  }
  if (MODE == 1){
    __syncthreads();
    #pragma unroll
    for (int r = 0; r < 4; r++){
      int row = sub*4 + r;
      float rm = __uint_as_float(rmaxs[row]);
      float qi = (rm > 0.f) ? 127.f/rm : 0.f;
      #pragma unroll
      for (int ntl = 0; ntl < 2; ntl++){
        int colg = wave*32 + ntl*16 + q;
        q8s[row][colg] = (char)(int)rintf(vv[r][ntl]*qi);
      }
    }
    if (threadIdx.x < 16){
      int node = tile + threadIdx.x;
      if (node < N){
        float rm = __uint_as_float(rmaxs[threadIdx.x]);
        scd_out[node] = rm * (1.f/127.f) * dinv[node];
      }
    }
    __syncthreads();
    if (threadIdx.x < 128){
      int row = threadIdx.x >> 3, c = threadIdx.x & 7;
      int node = tile + row;
      if (node < N) ((uint4*)gout)[(size_t)node*8 + c] = q8v[row][c];
    }
  }
}

extern "C" void kernel_launch(void* const* d_in, const int* in_sizes, int n_in,
                              void* d_out, int out_size, void* d_ws, size_t ws_size,
                              hipStream_t stream){
  const float* x      = (const float*)d_in[0];
  const int*   eidx   = (const int*)d_in[1];
  const float* emask  = (const float*)d_in[2];
  const float* W_gat  = (const float*)d_in[3];
  const float* a_src  = (const float*)d_in[4];
  const float* a_dst  = (const float*)d_in[5];
  const float* b_gat  = (const float*)d_in[6];
  const float* W_gcn  = (const float*)d_in[7];
  const float* b_gcn  = (const float*)d_in[8];
  int N = in_sizes[0] / HIDDEN;
  int E = in_sizes[1] / 2;
  const int* src = eidx;
  const int* dst = eidx + E;

  char* p = (char*)d_ws;
  auto carve = [&](size_t bytes)->char*{ char* q = p; p += align_up(bytes, 512); return q; };
  ushort_t* h0   = (ushort_t*)carve((size_t)N*HIDDEN*2);
  ushort_t* h1   = (ushort_t*)carve((size_t)N*HIDDEN*2);
  ushort_t* h2   = (ushort_t*)carve((size_t)N*HIDDEN*2);
  ushort_t* Wt   = (ushort_t*)carve((size_t)4*HIDDEN*HIDDEN*2);
  unsigned* zq   = (unsigned*)carve((size_t)N*HIDDEN);      // int8 matrices (128B rows)
  unsigned* g0q  = (unsigned*)carve((size_t)N*HIDDEN);
  unsigned* g1q  = (unsigned*)carve((size_t)N*HIDDEN);
  unsigned* g2q  = (unsigned*)carve((size_t)N*HIDDEN);
  float* scd0    = (float*)carve((size_t)N*4);
  float* scd1    = (float*)carve((size_t)N*4);
  float* scd2    = (float*)carve((size_t)N*4);
  float4* attr4  = (float4*)carve((size_t)N*16);
  float* sdst    = (float*)carve((size_t)N*4);
  float* dinv    = (float*)carve((size_t)N*4);
  int*   rowp    = (int*)  carve((size_t)(N+1)*4);
  int2*  col_sw  = (int2*) carve((size_t)E*8);
  int2*  tpw     = (int2*) carve((size_t)E*8);
  int nbkt = (N + 255) >> 8;                       // 196
  int M    = nbkt * P_SORT;                        // 50176
  int*   bcnt  = (int*)carve((size_t)M*4);
  int*   incl  = (int*)carve((size_t)M*4);
  int nbs = (M + 255) / 256;                       // == nbkt
  int*   blockSums = (int*)carve((size_t)nbs*4);
  (void)ws_size; (void)n_in; (void)out_size;

  int epb = (E + P_SORT - 1) / P_SORT;
  int gb  = (N + 63) / 64;
  int nwb = (N + 3) / 4;
  int nfb = (N + 15) / 16;

  // CSR build (atomic-free, full-chip); cast rides along in extra blocks
  k_b1cnt_cast<<<P_SORT + 256, 256, 0, stream>>>(dst, bcnt, W_gat, W_gcn, Wt, E, epb, nbkt);
  k_scan1  <<<nbs, 256, 0, stream>>>(bcnt, incl, blockSums, M);
  k_b1place<<<P_SORT, 256, 0, stream>>>(src, dst, emask, incl, bcnt, blockSums,
                                        tpw, E, epb, nbkt);
  k_b2     <<<nbkt, 256, 0, stream>>>(tpw, blockSums, col_sw, rowp, dinv, N, E, nbkt);

  // xp = x @ W_gat -> int8 rows + attr4 {src-dot, dinv, scale} + sdst
  k_gemm1<<<gb, 128, 0, stream>>>(x, Wt, zq, a_src, a_dst, dinv, attr4, sdst, N);

  // GAT aggregation (single fused sweep), produces h0 bf16 + g0 int8 + scd0
  k_agg0<<<nwb, 256, 0, stream>>>(zq, rowp, col_sw, attr4, sdst,
                                  b_gat, h0, g0q, scd0, N);

  // fused GCN layers: h' = relu((A h) W + b); edge coeffs cached per-block in LDS
  k_fagg<1><<<nfb, 256, 0, stream>>>(g0q, scd0, rowp, col_sw, dinv,
                                     Wt + (size_t)1*16384, b_gcn + 0,
                                     h1, g1q, scd1,
                                     nullptr, nullptr, nullptr, nullptr, N);
  k_fagg<1><<<nfb, 256, 0, stream>>>(g1q, scd1, rowp, col_sw, dinv,
                                     Wt + (size_t)2*16384, b_gcn + 128,
                                     h2, g2q, scd2,
                                     nullptr, nullptr, nullptr, nullptr, N);
  // last layer + fused JK max over {h0, h1, h2, h3} -> fp32 d_out
  k_fagg<2><<<nfb, 256, 0, stream>>>(g2q, scd2, rowp, col_sw, dinv,
                                     Wt + (size_t)3*16384, b_gcn + 256,
                                     nullptr, nullptr, nullptr,
                                     h0, h1, h2, (float*)d_out, N);
}